// Round 2
// baseline (664.836 us; speedup 1.0000x reference)
//
#include <hip/hip_runtime.h>
#include <math.h>

#define BATCH   32
#define N_BEADS 16384
#define BEAD_SIZE 16
#define N_ATOMS 100000
#define INV_SQRT2 0.70710678118654752440f

// One thread per (batch, valid-slot m).
// t = b*M + m so consecutive lanes share b and walk m -> coalesced index
// loads, coalesced rot writes, and high L1/L2 locality on p1/p2 (avg 8.5
// slots share one bead).
__global__ void __launch_bounds__(256)
backmap_kernel(const float* __restrict__ P,
               const float* __restrict__ p1,
               const float* __restrict__ p2,
               const float* __restrict__ W,      // (3, N_BEADS, 16)
               const float* __restrict__ ang,    // (M)
               const float* __restrict__ scal,   // (N_ATOMS)
               const int*  __restrict__ slot_idx,
               const int*  __restrict__ atom_idx,
               const int*  __restrict__ bead_idx,
               float* __restrict__ out_atoms,    // (B, N_ATOMS, 3)
               float* __restrict__ out_rot,      // (B*M, 3)
               int M)
{
    int t = blockIdx.x * blockDim.x + threadIdx.x;
    int total = BATCH * M;
    if (t >= total) return;
    int b = t / M;
    int m = t - b * M;

    int slot = slot_idx[m];
    int h = slot >> 4;        // bead owning this slot (for rot)
    int l = slot & 15;        // slot within bead
    int bead = bead_idx[m];   // bead for v / P gather (== h structurally)
    int atom = atom_idx[m];

    const float* p1p = p1 + ((size_t)b * N_BEADS + h) * 3;
    const float* p2p = p2 + ((size_t)b * N_BEADS + h) * 3;
    float a1x = p1p[0], a1y = p1p[1], a1z = p1p[2];
    float a2x = p2p[0], a2y = p2p[1], a2z = p2p[2];

    // p12 = cross(p1,p2) * 1/sqrt(2)
    float cx = (a1y * a2z - a1z * a2y) * INV_SQRT2;
    float cy = (a1z * a2x - a1x * a2z) * INV_SQRT2;
    float cz = (a1x * a2y - a1y * a2x) * INV_SQRT2;

    float w0 = W[(0 * N_BEADS + h) * BEAD_SIZE + l];
    float w1 = W[(1 * N_BEADS + h) * BEAD_SIZE + l];
    float w2 = W[(2 * N_BEADS + h) * BEAD_SIZE + l];

    // rot = w0*p1 + w1*p2 + w2*p12, normalized
    float rx = w0 * a1x + w1 * a2x + w2 * cx;
    float ry = w0 * a1y + w1 * a2y + w2 * cy;
    float rz = w0 * a1z + w1 * a2z + w2 * cz;
    float inv = rsqrtf(rx * rx + ry * ry + rz * rz);
    rx *= inv; ry *= inv; rz *= inv;

    // output 1: rot_flat (coalesced: 12 contiguous bytes per lane)
    float* ro = out_rot + ((size_t)b * M + m) * 3;
    ro[0] = rx; ro[1] = ry; ro[2] = rz;

    float a = ang[m];
    float sa, ca;
    __sincosf(a, &sa, &ca);

    // q = (cos a, sin a * rot)   — unit quaternion
    float qw = ca, qx = sa * rx, qy = sa * ry, qz = sa * rz;

    // v = p1[b, bead]
    const float* vp = p1 + ((size_t)b * N_BEADS + bead) * 3;
    float vx = vp[0], vy = vp[1], vz = vp[2];

    // tq = q * (0, v)
    float tw = -qx * vx - qy * vy - qz * vz;
    float tx =  qw * vx + qy * vz - qz * vy;
    float ty =  qw * vy + qz * vx - qx * vz;
    float tz =  qw * vz + qx * vy - qy * vx;
    // r = tq * conj(q)   (vector part)
    float vrx = -tw * qx + tx * qw - ty * qz + tz * qy;
    float vry = -tw * qy + ty * qw - tz * qx + tx * qz;
    float vrz = -tw * qz + tz * qw - tx * qy + ty * qx;

    float s = scal[atom];
    const float* Pp = P + ((size_t)b * N_BEADS + bead) * 3;
    float ox = s * vrx + Pp[0];
    float oy = s * vry + Pp[1];
    float oz = s * vrz + Pp[2];

    // output 0: scatter-add over atoms (avg 1.39 hits/atom/batch -> low contention)
    float* op = out_atoms + ((size_t)b * N_ATOMS + atom) * 3;
    atomicAdd(op + 0, ox);
    atomicAdd(op + 1, oy);
    atomicAdd(op + 2, oz);
}

extern "C" void kernel_launch(void* const* d_in, const int* in_sizes, int n_in,
                              void* d_out, int out_size, void* d_ws, size_t ws_size,
                              hipStream_t stream) {
    const float* P    = (const float*)d_in[0];
    const float* p1   = (const float*)d_in[1];
    const float* p2   = (const float*)d_in[2];
    const float* W    = (const float*)d_in[3];
    const float* ang  = (const float*)d_in[4];
    const float* scal = (const float*)d_in[5];
    const int* slot_idx = (const int*)d_in[6];
    const int* atom_idx = (const int*)d_in[7];
    const int* bead_idx = (const int*)d_in[8];

    int M = in_sizes[6];                       // slot_idx length
    float* out_atoms = (float*)d_out;          // B*N_ATOMS*3 floats
    float* out_rot   = out_atoms + (size_t)BATCH * N_ATOMS * 3;

    // zero the scatter target each call (harness does not re-poison)
    hipMemsetAsync(out_atoms, 0, (size_t)BATCH * N_ATOMS * 3 * sizeof(float), stream);

    int total = BATCH * M;
    int block = 256;
    int grid = (total + block - 1) / block;
    backmap_kernel<<<grid, block, 0, stream>>>(P, p1, p2, W, ang, scal,
                                               slot_idx, atom_idx, bead_idx,
                                               out_atoms, out_rot, M);
}

// Round 3
// 234.059 us; speedup vs baseline: 2.8405x; 2.8405x over previous
//
#include <hip/hip_runtime.h>
#include <math.h>

#define BATCH   32
#define N_BEADS 16384
#define BEAD_SIZE 16
#define N_ATOMS 100000
#define INV_SQRT2 0.70710678118654752440f
#define CAP 20   // max contributors per atom; Poisson(1.39) => P(>=20) ~ 0

// ---------------- pass 0: bucket build (per m) ----------------
// cursor[a]   : contributor count per atom
// bucket[a*CAP+k] : the m indices contributing to atom a
// rec[3*m]    : {bead (as bits), cos(ang), sin(ang)} per m
__global__ void __launch_bounds__(256)
build_kernel(const int* __restrict__ atom_idx,
             const int* __restrict__ bead_idx,
             const float* __restrict__ ang,
             int* __restrict__ cursor,
             int* __restrict__ bucket,
             float* __restrict__ rec,
             int M)
{
    int m = blockIdx.x * blockDim.x + threadIdx.x;
    if (m >= M) return;
    int a = atom_idx[m];
    int pos = atomicAdd(&cursor[a], 1);
    if (pos < CAP) bucket[a * CAP + pos] = m;
    float sa, ca;
    __sincosf(ang[m], &sa, &ca);
    rec[3 * m + 0] = __int_as_float(bead_idx[m]);
    rec[3 * m + 1] = ca;
    rec[3 * m + 2] = sa;
}

// ---------------- pass 1: rot (per b,m) — coalesced write ----------------
__global__ void __launch_bounds__(256)
rot_kernel(const float* __restrict__ p1,
           const float* __restrict__ p2,
           const float* __restrict__ W,       // (3, N_BEADS, 16)
           const int*  __restrict__ slot_idx,
           float* __restrict__ out_rot,       // (B*M, 3)
           int M)
{
    int t = blockIdx.x * blockDim.x + threadIdx.x;
    int total = BATCH * M;
    if (t >= total) return;
    int b = t / M;
    int m = t - b * M;

    int slot = slot_idx[m];
    int h = slot >> 4;
    int l = slot & 15;

    const float* p1p = p1 + ((size_t)b * N_BEADS + h) * 3;
    const float* p2p = p2 + ((size_t)b * N_BEADS + h) * 3;
    float a1x = p1p[0], a1y = p1p[1], a1z = p1p[2];
    float a2x = p2p[0], a2y = p2p[1], a2z = p2p[2];

    float cx = (a1y * a2z - a1z * a2y) * INV_SQRT2;
    float cy = (a1z * a2x - a1x * a2z) * INV_SQRT2;
    float cz = (a1x * a2y - a1y * a2x) * INV_SQRT2;

    float w0 = W[(0 * N_BEADS + h) * BEAD_SIZE + l];
    float w1 = W[(1 * N_BEADS + h) * BEAD_SIZE + l];
    float w2 = W[(2 * N_BEADS + h) * BEAD_SIZE + l];

    float rx = w0 * a1x + w1 * a2x + w2 * cx;
    float ry = w0 * a1y + w1 * a2y + w2 * cy;
    float rz = w0 * a1z + w1 * a2z + w2 * cz;
    float inv = rsqrtf(rx * rx + ry * ry + rz * rz);
    rx *= inv; ry *= inv; rz *= inv;

    float* ro = out_rot + (size_t)t * 3;
    ro[0] = rx; ro[1] = ry; ro[2] = rz;
}

// ---------------- pass 2: gather per (b, atom) — zero atomics ----------------
__global__ void __launch_bounds__(256)
atoms_kernel(const float* __restrict__ P,
             const float* __restrict__ p1,
             const float* __restrict__ scal,
             const int*  __restrict__ cursor,
             const int*  __restrict__ bucket,
             const float* __restrict__ rec,
             const float* __restrict__ out_rot,
             float* __restrict__ out_atoms,    // (B, N_ATOMS, 3)
             int M)
{
    int t = blockIdx.x * blockDim.x + threadIdx.x;
    if (t >= BATCH * N_ATOMS) return;
    int b = t / N_ATOMS;
    int a = t - b * N_ATOMS;

    int cnt = cursor[a];
    cnt = cnt < CAP ? cnt : CAP;
    float s = scal[a];

    float ax = 0.f, ay = 0.f, az = 0.f;
    for (int k = 0; k < cnt; ++k) {
        int m = bucket[a * CAP + k];
        float rb = rec[3 * m + 0];
        float ca = rec[3 * m + 1];
        float sa = rec[3 * m + 2];
        int bead = __float_as_int(rb);

        const float* ro = out_rot + ((size_t)b * M + m) * 3;
        float rx = ro[0], ry = ro[1], rz = ro[2];

        float qw = ca, qx = sa * rx, qy = sa * ry, qz = sa * rz;

        const float* vp = p1 + ((size_t)b * N_BEADS + bead) * 3;
        float vx = vp[0], vy = vp[1], vz = vp[2];

        float tw = -qx * vx - qy * vy - qz * vz;
        float tx =  qw * vx + qy * vz - qz * vy;
        float ty =  qw * vy + qz * vx - qx * vz;
        float tz =  qw * vz + qx * vy - qy * vx;
        float vrx = -tw * qx + tx * qw - ty * qz + tz * qy;
        float vry = -tw * qy + ty * qw - tz * qx + tx * qz;
        float vrz = -tw * qz + tz * qw - tx * qy + ty * qx;

        const float* Pp = P + ((size_t)b * N_BEADS + bead) * 3;
        ax += s * vrx + Pp[0];
        ay += s * vry + Pp[1];
        az += s * vrz + Pp[2];
    }

    float* op = out_atoms + (size_t)t * 3;
    op[0] = ax; op[1] = ay; op[2] = az;
}

// ---------------- fallback (round-2 path) if ws too small ----------------
__global__ void __launch_bounds__(256)
backmap_fallback(const float* __restrict__ P, const float* __restrict__ p1,
                 const float* __restrict__ p2, const float* __restrict__ W,
                 const float* __restrict__ ang, const float* __restrict__ scal,
                 const int* __restrict__ slot_idx, const int* __restrict__ atom_idx,
                 const int* __restrict__ bead_idx,
                 float* __restrict__ out_atoms, float* __restrict__ out_rot, int M)
{
    int t = blockIdx.x * blockDim.x + threadIdx.x;
    if (t >= BATCH * M) return;
    int b = t / M; int m = t - b * M;
    int slot = slot_idx[m]; int h = slot >> 4; int l = slot & 15;
    int bead = bead_idx[m]; int atom = atom_idx[m];
    const float* p1p = p1 + ((size_t)b * N_BEADS + h) * 3;
    const float* p2p = p2 + ((size_t)b * N_BEADS + h) * 3;
    float a1x = p1p[0], a1y = p1p[1], a1z = p1p[2];
    float a2x = p2p[0], a2y = p2p[1], a2z = p2p[2];
    float cx = (a1y * a2z - a1z * a2y) * INV_SQRT2;
    float cy = (a1z * a2x - a1x * a2z) * INV_SQRT2;
    float cz = (a1x * a2y - a1y * a2x) * INV_SQRT2;
    float w0 = W[(0 * N_BEADS + h) * BEAD_SIZE + l];
    float w1 = W[(1 * N_BEADS + h) * BEAD_SIZE + l];
    float w2 = W[(2 * N_BEADS + h) * BEAD_SIZE + l];
    float rx = w0 * a1x + w1 * a2x + w2 * cx;
    float ry = w0 * a1y + w1 * a2y + w2 * cy;
    float rz = w0 * a1z + w1 * a2z + w2 * cz;
    float inv = rsqrtf(rx * rx + ry * ry + rz * rz);
    rx *= inv; ry *= inv; rz *= inv;
    float* ro = out_rot + (size_t)t * 3;
    ro[0] = rx; ro[1] = ry; ro[2] = rz;
    float sa, ca; __sincosf(ang[m], &sa, &ca);
    float qw = ca, qx = sa * rx, qy = sa * ry, qz = sa * rz;
    const float* vp = p1 + ((size_t)b * N_BEADS + bead) * 3;
    float vx = vp[0], vy = vp[1], vz = vp[2];
    float tw = -qx * vx - qy * vy - qz * vz;
    float tx =  qw * vx + qy * vz - qz * vy;
    float ty =  qw * vy + qz * vx - qx * vz;
    float tz =  qw * vz + qx * vy - qy * vx;
    float vrx = -tw * qx + tx * qw - ty * qz + tz * qy;
    float vry = -tw * qy + ty * qw - tz * qx + tx * qz;
    float vrz = -tw * qz + tz * qw - tx * qy + ty * qx;
    float s = scal[atom];
    const float* Pp = P + ((size_t)b * N_BEADS + bead) * 3;
    float* op = out_atoms + ((size_t)b * N_ATOMS + atom) * 3;
    atomicAdd(op + 0, s * vrx + Pp[0]);
    atomicAdd(op + 1, s * vry + Pp[1]);
    atomicAdd(op + 2, s * vrz + Pp[2]);
}

extern "C" void kernel_launch(void* const* d_in, const int* in_sizes, int n_in,
                              void* d_out, int out_size, void* d_ws, size_t ws_size,
                              hipStream_t stream) {
    const float* P    = (const float*)d_in[0];
    const float* p1   = (const float*)d_in[1];
    const float* p2   = (const float*)d_in[2];
    const float* W    = (const float*)d_in[3];
    const float* ang  = (const float*)d_in[4];
    const float* scal = (const float*)d_in[5];
    const int* slot_idx = (const int*)d_in[6];
    const int* atom_idx = (const int*)d_in[7];
    const int* bead_idx = (const int*)d_in[8];

    int M = in_sizes[6];
    float* out_atoms = (float*)d_out;
    float* out_rot   = out_atoms + (size_t)BATCH * N_ATOMS * 3;

    // ws layout: cursor[N_ATOMS] | bucket[N_ATOMS*CAP] | rec[3*M]
    size_t need = (size_t)N_ATOMS * 4 + (size_t)N_ATOMS * CAP * 4 + (size_t)M * 12;
    if (ws_size < need) {
        // fallback: atomic scatter (round-2 kernel)
        hipMemsetAsync(out_atoms, 0, (size_t)BATCH * N_ATOMS * 3 * sizeof(float), stream);
        int total = BATCH * M;
        backmap_fallback<<<(total + 255) / 256, 256, 0, stream>>>(
            P, p1, p2, W, ang, scal, slot_idx, atom_idx, bead_idx,
            out_atoms, out_rot, M);
        return;
    }

    int*   cursor = (int*)d_ws;
    int*   bucket = cursor + N_ATOMS;
    float* rec    = (float*)(bucket + (size_t)N_ATOMS * CAP);

    hipMemsetAsync(cursor, 0, (size_t)N_ATOMS * sizeof(int), stream);

    build_kernel<<<(M + 255) / 256, 256, 0, stream>>>(
        atom_idx, bead_idx, ang, cursor, bucket, rec, M);

    int total1 = BATCH * M;
    rot_kernel<<<(total1 + 255) / 256, 256, 0, stream>>>(
        p1, p2, W, slot_idx, out_rot, M);

    int total2 = BATCH * N_ATOMS;
    atoms_kernel<<<(total2 + 255) / 256, 256, 0, stream>>>(
        P, p1, scal, cursor, bucket, rec, out_rot, out_atoms, M);
}

// Round 4
// 109.097 us; speedup vs baseline: 6.0940x; 2.1454x over previous
//
#include <hip/hip_runtime.h>
#include <math.h>

#define BATCH   32
#define N_BEADS 16384
#define BEAD_SIZE 16
#define N_ATOMS 100000
#define INV_SQRT2 0.70710678118654752440f
#define CAP 20
#define SCAN_BLK 256

// ============================ CSR build chain ============================
__global__ void __launch_bounds__(256)
count_kernel(const int* __restrict__ atom_idx, int* __restrict__ counts, int M)
{
    int m = blockIdx.x * blockDim.x + threadIdx.x;
    if (m < M) atomicAdd(&counts[atom_idx[m]], 1);
}

// per-block exclusive scan; block sums out
__global__ void __launch_bounds__(SCAN_BLK)
scan1_kernel(const int* __restrict__ counts, int* __restrict__ off,
             int* __restrict__ bsum, int n)
{
    __shared__ int s[SCAN_BLK];
    int i = blockIdx.x * SCAN_BLK + threadIdx.x;
    int c = (i < n) ? counts[i] : 0;
    s[threadIdx.x] = c;
    __syncthreads();
    int v = c;
    for (int d = 1; d < SCAN_BLK; d <<= 1) {
        int t = (threadIdx.x >= d) ? s[threadIdx.x - d] : 0;
        __syncthreads();
        v += t;
        s[threadIdx.x] = v;
        __syncthreads();
    }
    if (i < n) off[i] = v - c;                    // exclusive within block
    if (threadIdx.x == SCAN_BLK - 1) bsum[blockIdx.x] = v;
}

// single-block exclusive scan of block sums (nb <= 512)
__global__ void __launch_bounds__(512)
scan2_kernel(const int* __restrict__ bsum, int* __restrict__ bsum2, int nb)
{
    __shared__ int s[512];
    int i = threadIdx.x;
    int c = (i < nb) ? bsum[i] : 0;
    s[i] = c;
    __syncthreads();
    int v = c;
    for (int d = 1; d < 512; d <<= 1) {
        int t = (i >= d) ? s[i - d] : 0;
        __syncthreads();
        v += t;
        s[i] = v;
        __syncthreads();
    }
    if (i < nb) bsum2[i] = v - c;
}

// add block offsets; zero fill-cursor
__global__ void __launch_bounds__(256)
scan3_kernel(int* __restrict__ off, const int* __restrict__ bsum2,
             int* __restrict__ cursor2, int n)
{
    int i = blockIdx.x * blockDim.x + threadIdx.x;
    if (i < n) { off[i] += bsum2[i / SCAN_BLK]; cursor2[i] = 0; }
}

__global__ void __launch_bounds__(256)
fill_kernel(const int* __restrict__ atom_idx, const int* __restrict__ off,
            int* __restrict__ cursor2, int* __restrict__ csr_m, int M)
{
    int m = blockIdx.x * blockDim.x + threadIdx.x;
    if (m >= M) return;
    int a = atom_idx[m];
    int k = atomicAdd(&cursor2[a], 1);
    csr_m[off[a] + k] = m;
}

// ================= pass 1: fully fused per (b,m) — all writes coalesced =================
// bead_idx[m] == slot_idx[m]>>4 structurally, so v = p1[b,h] and P[b,h] are
// already at hand -> compute the complete contribution here.
__global__ void __launch_bounds__(256)
fused_kernel(const float* __restrict__ P,
             const float* __restrict__ p1,
             const float* __restrict__ p2,
             const float* __restrict__ W,        // (3, N_BEADS, 16)
             const float* __restrict__ ang,      // (M)
             const float* __restrict__ scal,     // (N_ATOMS)
             const int*  __restrict__ slot_idx,
             const int*  __restrict__ atom_idx,
             float* __restrict__ out_rot,        // (B, M, 3)
             float* __restrict__ contrib,        // (B, M, 3) ws
             int M)
{
    int t = blockIdx.x * blockDim.x + threadIdx.x;
    if (t >= BATCH * M) return;
    int b = t / M;
    int m = t - b * M;

    int slot = slot_idx[m];
    int h = slot >> 4;
    int l = slot & 15;

    const float* p1p = p1 + ((size_t)b * N_BEADS + h) * 3;
    const float* p2p = p2 + ((size_t)b * N_BEADS + h) * 3;
    float a1x = p1p[0], a1y = p1p[1], a1z = p1p[2];
    float a2x = p2p[0], a2y = p2p[1], a2z = p2p[2];

    float cx = (a1y * a2z - a1z * a2y) * INV_SQRT2;
    float cy = (a1z * a2x - a1x * a2z) * INV_SQRT2;
    float cz = (a1x * a2y - a1y * a2x) * INV_SQRT2;

    float w0 = W[(0 * N_BEADS + h) * BEAD_SIZE + l];
    float w1 = W[(1 * N_BEADS + h) * BEAD_SIZE + l];
    float w2 = W[(2 * N_BEADS + h) * BEAD_SIZE + l];

    float rx = w0 * a1x + w1 * a2x + w2 * cx;
    float ry = w0 * a1y + w1 * a2y + w2 * cy;
    float rz = w0 * a1z + w1 * a2z + w2 * cz;
    float inv = rsqrtf(rx * rx + ry * ry + rz * rz);
    rx *= inv; ry *= inv; rz *= inv;

    float* ro = out_rot + (size_t)t * 3;
    ro[0] = rx; ro[1] = ry; ro[2] = rz;

    float sa, ca;
    __sincosf(ang[m], &sa, &ca);
    float qw = ca, qx = sa * rx, qy = sa * ry, qz = sa * rz;

    // v = p1[b, bead] == (a1x,a1y,a1z)
    float tw = -qx * a1x - qy * a1y - qz * a1z;
    float tx =  qw * a1x + qy * a1z - qz * a1y;
    float ty =  qw * a1y + qz * a1x - qx * a1z;
    float tz =  qw * a1z + qx * a1y - qy * a1x;
    float vrx = -tw * qx + tx * qw - ty * qz + tz * qy;
    float vry = -tw * qy + ty * qw - tz * qx + tx * qz;
    float vrz = -tw * qz + tz * qw - tx * qy + ty * qx;

    float s = scal[atom_idx[m]];                 // 0.4 MB table, L2-resident
    const float* Pp = P + ((size_t)b * N_BEADS + h) * 3;

    float* cp = contrib + (size_t)t * 3;
    cp[0] = s * vrx + Pp[0];
    cp[1] = s * vry + Pp[1];
    cp[2] = s * vrz + Pp[2];
}

// ================= pass 2: pure CSR sum, XCD-swizzled over b =================
// XCD x handles b = x, x+8, x+16, x+24 in sequence -> the 1.67 MB contrib
// b-slice stays resident in that XCD's 4 MB L2 for the random 12B gathers.
__global__ void __launch_bounds__(256)
sum_kernel(const int* __restrict__ counts,
           const int* __restrict__ off,
           const int* __restrict__ csr_m,
           const float* __restrict__ contrib,   // (B, M, 3)
           float* __restrict__ out_atoms,       // (B, N_ATOMS, 3)
           int M, int abps)                     // abps = ceil(N_ATOMS/256)
{
    int beta = blockIdx.x;
    int xcd  = beta & 7;
    int j    = beta >> 3;
    int round = j / abps;                        // 0..3
    int ablk  = j - round * abps;
    int b = xcd + 8 * round;

    int a = ablk * 256 + threadIdx.x;
    if (a >= N_ATOMS) return;

    int cnt = counts[a];
    int o   = off[a];
    const float* cb = contrib + (size_t)b * M * 3;

    float ax = 0.f, ay = 0.f, az = 0.f;
    for (int k = 0; k < cnt; ++k) {
        int m = csr_m[o + k];
        const float* cp = cb + (size_t)m * 3;
        ax += cp[0]; ay += cp[1]; az += cp[2];
    }
    float* op = out_atoms + ((size_t)b * N_ATOMS + a) * 3;
    op[0] = ax; op[1] = ay; op[2] = az;
}

// ================= fallback (round-3 bucket path, ws >= 10.1 MB) =================
__global__ void __launch_bounds__(256)
fb_build(const int* __restrict__ atom_idx, const int* __restrict__ bead_idx,
         const float* __restrict__ ang, int* __restrict__ cursor,
         int* __restrict__ bucket, float* __restrict__ rec, int M)
{
    int m = blockIdx.x * blockDim.x + threadIdx.x;
    if (m >= M) return;
    int a = atom_idx[m];
    int pos = atomicAdd(&cursor[a], 1);
    if (pos < CAP) bucket[a * CAP + pos] = m;
    float sa, ca; __sincosf(ang[m], &sa, &ca);
    rec[3 * m + 0] = __int_as_float(bead_idx[m]);
    rec[3 * m + 1] = ca;
    rec[3 * m + 2] = sa;
}

__global__ void __launch_bounds__(256)
fb_rot(const float* __restrict__ p1, const float* __restrict__ p2,
       const float* __restrict__ W, const int* __restrict__ slot_idx,
       float* __restrict__ out_rot, int M)
{
    int t = blockIdx.x * blockDim.x + threadIdx.x;
    if (t >= BATCH * M) return;
    int b = t / M; int m = t - b * M;
    int slot = slot_idx[m]; int h = slot >> 4; int l = slot & 15;
    const float* p1p = p1 + ((size_t)b * N_BEADS + h) * 3;
    const float* p2p = p2 + ((size_t)b * N_BEADS + h) * 3;
    float a1x = p1p[0], a1y = p1p[1], a1z = p1p[2];
    float a2x = p2p[0], a2y = p2p[1], a2z = p2p[2];
    float cx = (a1y * a2z - a1z * a2y) * INV_SQRT2;
    float cy = (a1z * a2x - a1x * a2z) * INV_SQRT2;
    float cz = (a1x * a2y - a1y * a2x) * INV_SQRT2;
    float w0 = W[(0 * N_BEADS + h) * BEAD_SIZE + l];
    float w1 = W[(1 * N_BEADS + h) * BEAD_SIZE + l];
    float w2 = W[(2 * N_BEADS + h) * BEAD_SIZE + l];
    float rx = w0 * a1x + w1 * a2x + w2 * cx;
    float ry = w0 * a1y + w1 * a2y + w2 * cy;
    float rz = w0 * a1z + w1 * a2z + w2 * cz;
    float inv = rsqrtf(rx * rx + ry * ry + rz * rz);
    rx *= inv; ry *= inv; rz *= inv;
    float* ro = out_rot + (size_t)t * 3;
    ro[0] = rx; ro[1] = ry; ro[2] = rz;
}

__global__ void __launch_bounds__(256)
fb_atoms(const float* __restrict__ P, const float* __restrict__ p1,
         const float* __restrict__ scal, const int* __restrict__ cursor,
         const int* __restrict__ bucket, const float* __restrict__ rec,
         const float* __restrict__ out_rot, float* __restrict__ out_atoms, int M)
{
    int t = blockIdx.x * blockDim.x + threadIdx.x;
    if (t >= BATCH * N_ATOMS) return;
    int b = t / N_ATOMS; int a = t - b * N_ATOMS;
    int cnt = cursor[a]; cnt = cnt < CAP ? cnt : CAP;
    float s = scal[a];
    float ax = 0.f, ay = 0.f, az = 0.f;
    for (int k = 0; k < cnt; ++k) {
        int m = bucket[a * CAP + k];
        float rb = rec[3 * m + 0], ca = rec[3 * m + 1], sa = rec[3 * m + 2];
        int bead = __float_as_int(rb);
        const float* ro = out_rot + ((size_t)b * M + m) * 3;
        float rx = ro[0], ry = ro[1], rz = ro[2];
        float qw = ca, qx = sa * rx, qy = sa * ry, qz = sa * rz;
        const float* vp = p1 + ((size_t)b * N_BEADS + bead) * 3;
        float vx = vp[0], vy = vp[1], vz = vp[2];
        float tw = -qx * vx - qy * vy - qz * vz;
        float tx =  qw * vx + qy * vz - qz * vy;
        float ty =  qw * vy + qz * vx - qx * vz;
        float tz =  qw * vz + qx * vy - qy * vx;
        float vrx = -tw * qx + tx * qw - ty * qz + tz * qy;
        float vry = -tw * qy + ty * qw - tz * qx + tx * qz;
        float vrz = -tw * qz + tz * qw - tx * qy + ty * qx;
        const float* Pp = P + ((size_t)b * N_BEADS + bead) * 3;
        ax += s * vrx + Pp[0]; ay += s * vry + Pp[1]; az += s * vrz + Pp[2];
    }
    float* op = out_atoms + (size_t)t * 3;
    op[0] = ax; op[1] = ay; op[2] = az;
}

extern "C" void kernel_launch(void* const* d_in, const int* in_sizes, int n_in,
                              void* d_out, int out_size, void* d_ws, size_t ws_size,
                              hipStream_t stream) {
    const float* P    = (const float*)d_in[0];
    const float* p1   = (const float*)d_in[1];
    const float* p2   = (const float*)d_in[2];
    const float* W    = (const float*)d_in[3];
    const float* ang  = (const float*)d_in[4];
    const float* scal = (const float*)d_in[5];
    const int* slot_idx = (const int*)d_in[6];
    const int* atom_idx = (const int*)d_in[7];
    const int* bead_idx = (const int*)d_in[8];

    int M = in_sizes[6];
    float* out_atoms = (float*)d_out;
    float* out_rot   = out_atoms + (size_t)BATCH * N_ATOMS * 3;

    int nblk  = (N_ATOMS + SCAN_BLK - 1) / SCAN_BLK;    // 391
    // ws layout: counts | off | cursor2 | bsum | bsum2 | csr_m | contrib
    size_t need = (size_t)N_ATOMS * 4 * 3 + 512 * 4 * 2
                + (size_t)M * 4 + (size_t)BATCH * M * 3 * 4;

    if (ws_size >= need) {
        int*   counts  = (int*)d_ws;
        int*   off     = counts + N_ATOMS;
        int*   cursor2 = off + N_ATOMS;
        int*   bsum    = cursor2 + N_ATOMS;
        int*   bsum2   = bsum + 512;
        int*   csr_m   = bsum2 + 512;
        float* contrib = (float*)(csr_m + M);

        hipMemsetAsync(counts, 0, (size_t)N_ATOMS * sizeof(int), stream);
        count_kernel<<<(M + 255) / 256, 256, 0, stream>>>(atom_idx, counts, M);
        scan1_kernel<<<nblk, SCAN_BLK, 0, stream>>>(counts, off, bsum, N_ATOMS);
        scan2_kernel<<<1, 512, 0, stream>>>(bsum, bsum2, nblk);
        scan3_kernel<<<nblk, 256, 0, stream>>>(off, bsum2, cursor2, N_ATOMS);
        fill_kernel<<<(M + 255) / 256, 256, 0, stream>>>(atom_idx, off, cursor2, csr_m, M);

        int total1 = BATCH * M;
        fused_kernel<<<(total1 + 255) / 256, 256, 0, stream>>>(
            P, p1, p2, W, ang, scal, slot_idx, atom_idx, out_rot, contrib, M);

        int abps = (N_ATOMS + 255) / 256;                // 391
        int grid2 = abps * BATCH;                        // 12512, 4 rounds x 8 XCDs
        sum_kernel<<<grid2, 256, 0, stream>>>(
            counts, off, csr_m, contrib, out_atoms, M, abps);
        return;
    }

    // ---- fallback: round-3 bucket design (needs ~10.1 MB) ----
    int*   cursor = (int*)d_ws;
    int*   bucket = cursor + N_ATOMS;
    float* rec    = (float*)(bucket + (size_t)N_ATOMS * CAP);
    hipMemsetAsync(cursor, 0, (size_t)N_ATOMS * sizeof(int), stream);
    fb_build<<<(M + 255) / 256, 256, 0, stream>>>(atom_idx, bead_idx, ang,
                                                  cursor, bucket, rec, M);
    int total1 = BATCH * M;
    fb_rot<<<(total1 + 255) / 256, 256, 0, stream>>>(p1, p2, W, slot_idx, out_rot, M);
    int total2 = BATCH * N_ATOMS;
    fb_atoms<<<(total2 + 255) / 256, 256, 0, stream>>>(P, p1, scal, cursor, bucket,
                                                       rec, out_rot, out_atoms, M);
}